// Round 3
// baseline (177.231 us; speedup 1.0000x reference)
//
#include <hip/hip_runtime.h>
#include <hip/hip_bf16.h>
#include <math.h>

// Problem constants
#define NB    4096
#define DH    784
#define KX    800            // 784 padded to 25*32 for BK=32 MFMA loop
#define NSR   5
#define NNEG  (NB*NSR)       // 20480
#define NTOT  (NB + NNEG)    // 24576

#define A_CONST 1.576943f
#define PEXP    1.7901216f   // 2*B_PARAM
#define EPS_C   1.0e-4f
#define ALPHA_C 0.9296875f   // BATCH_COUNT=500: beta=0.5*(1-500/800)^2=0.0703125
#define BETA_C  0.0703125f

#define NSLOT 64             // per row: 32 block-contribs x 2 wave-halves
#define SLAB  (NB * NSLOT)   // elements per stat component = 262144
#define NBLK  528            // upper-triangular 32x32 block grid

typedef __hip_bfloat16 bf16;
typedef short bf16x8 __attribute__((ext_vector_type(8)));
typedef float f32x4  __attribute__((ext_vector_type(4)));

// Workspace layout (bytes)
#define WS_XBF    0                      // 4096*800*2 = 6553600
#define WS_EBF    6553600                // 4096*32*2  = 262144
#define WS_SQX    6815744                // 4096*4     = 16384
#define WS_SQE    6832128                // 4096*4     = 16384
#define WS_STATSP 6848512                // 5*262144*4 = 5242880
#define WS_UPART  12091392               // 96*4       = 384
#define WS_CPART  12091776               // 64*4       = 256

__device__ __forceinline__ void gl2lds16(const bf16* g, bf16* l) {
    __builtin_amdgcn_global_load_lds(
        (const __attribute__((address_space(1))) unsigned int*)g,
        (__attribute__((address_space(3))) unsigned int*)l,
        16, 0, 0);
}

// ---- prep: X (4096x784 f32) -> bf16 padded 4096x800 + row sq-norms.
// 4 waves/block, one row per wave, float4 loads. 196 float4 per row.
__global__ void prep_x(const float* __restrict__ X, bf16* __restrict__ Xbf,
                       float* __restrict__ sqx) {
    const int wave = threadIdx.x >> 6, lane = threadIdx.x & 63;
    const int row = blockIdx.x * 4 + wave;
    const float4* xr = (const float4*)(X + (size_t)row * DH);
    bf16* xb = Xbf + (size_t)row * KX;
    float s = 0.f;
    #pragma unroll
    for (int it = 0; it < 4; ++it) {
        const int idx = lane + it * 64;
        if (idx < 196) {
            float4 v = xr[idx];
            s += v.x * v.x + v.y * v.y + v.z * v.z + v.w * v.w;
            union { bf16 h[4]; ushort4 u; } cv;
            cv.h[0] = __float2bfloat16(v.x);
            cv.h[1] = __float2bfloat16(v.y);
            cv.h[2] = __float2bfloat16(v.z);
            cv.h[3] = __float2bfloat16(v.w);
            *(ushort4*)(xb + idx * 4) = cv.u;
        }
    }
    if (lane < 16) xb[DH + lane] = __float2bfloat16(0.f);   // pad 784..799
    #pragma unroll
    for (int off = 32; off; off >>= 1) s += __shfl_down(s, off, 64);
    if (lane == 0) sqx[row] = s;
}

// ---- fused: UMAP CE partial sums + e_to -> bf16 (4096x32, upper half zero) + sqe
__global__ void umap_prep_e(const float* __restrict__ emb, const int* __restrict__ perm,
                            bf16* __restrict__ Ebf, float* __restrict__ sqe,
                            float* __restrict__ upart) {
    const int t = blockIdx.x * 256 + threadIdx.x;
    float val = 0.f;
    if (t < NB) {
        const float4* av = (const float4*)(emb + (size_t)t * 32);
        float4 t0 = av[0], t1 = av[1], t2 = av[2], t3 = av[3];   // e_to
        float4 f0 = av[4], f1 = av[5], f2 = av[6], f3 = av[7];   // e_from
        // write bf16 e_to row (padded with zeros)
        bf16* eb = Ebf + (size_t)t * 32;
        union { bf16 h[4]; ushort4 u; } cv;
        #define ST4(dst, q) cv.h[0]=__float2bfloat16(q.x); cv.h[1]=__float2bfloat16(q.y); \
                            cv.h[2]=__float2bfloat16(q.z); cv.h[3]=__float2bfloat16(q.w); \
                            *(ushort4*)(dst) = cv.u;
        ST4(eb,      t0) ST4(eb + 4,  t1) ST4(eb + 8,  t2) ST4(eb + 12, t3)
        #undef ST4
        ushort4 z = {0, 0, 0, 0};
        *(ushort4*)(eb + 16) = z; *(ushort4*)(eb + 20) = z;
        *(ushort4*)(eb + 24) = z; *(ushort4*)(eb + 28) = z;
        sqe[t] = t0.x*t0.x + t0.y*t0.y + t0.z*t0.z + t0.w*t0.w
               + t1.x*t1.x + t1.y*t1.y + t1.z*t1.z + t1.w*t1.w
               + t2.x*t2.x + t2.y*t2.y + t2.z*t2.z + t2.w*t2.w
               + t3.x*t3.x + t3.y*t3.y + t3.z*t3.z + t3.w*t3.w;
        float d2 = 0.f;
        #define D2(a, b) { float4 df = {a.x-b.x, a.y-b.y, a.z-b.z, a.w-b.w}; \
                           d2 += df.x*df.x + df.y*df.y + df.z*df.z + df.w*df.w; }
        D2(t0, f0) D2(t1, f1) D2(t2, f2) D2(t3, f3)
        #undef D2
        float d = sqrtf(d2);
        float p = 1.f / (1.f + A_CONST * powf(d, PEXP));
        val = -logf(fminf(fmaxf(p, EPS_C), 1.f));
    } else if (t < NTOT) {
        const int k = t - NB;
        const int ti = k / 5;
        const int fi = perm[k] / 5;
        const float4* at = (const float4*)(emb + (size_t)ti * 32);
        const float4* bt = (const float4*)(emb + (size_t)fi * 32 + 16);
        float d2 = 0.f;
        #pragma unroll
        for (int q = 0; q < 4; ++q) {
            float4 a = at[q], b = bt[q];
            float4 df = {a.x-b.x, a.y-b.y, a.z-b.z, a.w-b.w};
            d2 += df.x*df.x + df.y*df.y + df.z*df.z + df.w*df.w;
        }
        float d = sqrtf(d2);
        float p = 1.f / (1.f + A_CONST * powf(d, PEXP));
        val = -logf(fminf(fmaxf(1.f - p, EPS_C), 1.f));
    }
    #pragma unroll
    for (int off = 32; off; off >>= 1) val += __shfl_down(val, off, 64);
    __shared__ float ps[4];
    if ((threadIdx.x & 63) == 0) ps[threadIdx.x >> 6] = val;
    __syncthreads();
    if (threadIdx.x == 0) upart[blockIdx.x] = ps[0] + ps[1] + ps[2] + ps[3];
}

// ---- main: upper-triangular 128x128 dual-gram + fused symmetric stats epilogue.
// LDS layout XOR-swizzled: row r's 16B seg at position p holds global seg
// p ^ ((r>>1)&3)  -> fragment ds_read_b128 is 2-way (free) instead of 8-way.
__global__ __launch_bounds__(256) void gram_kernel(
    const bf16* __restrict__ Xbf, const bf16* __restrict__ Ebf,
    const float* __restrict__ sqx, const float* __restrict__ sqe,
    float* __restrict__ statsp) {
    __shared__ bf16 As[128 * 32];   // 8 KB
    __shared__ bf16 Bs[128 * 32];   // 8 KB
    __shared__ float sqxs[256];     // [0..127]=i rows, [128..255]=j cols
    __shared__ float sqes[256];

    // triangular decode: blockIdx.x -> (bi, bj), bi <= bj
    int n = blockIdx.x, bi = 0;
    while (n >= 32 - bi) { n -= 32 - bi; ++bi; }
    const int bj = bi + n;
    const int i0 = bi * 128, j0 = bj * 128;

    const int tid  = threadIdx.x;
    const int wave = tid >> 6;
    const int lane = tid & 63;
    const int wy = wave >> 1, wx = wave & 1;
    const int quad = lane >> 4, l15 = lane & 15;

    f32x4 acc[4][4];
    #pragma unroll
    for (int a = 0; a < 4; ++a)
        #pragma unroll
        for (int b = 0; b < 4; ++b)
            acc[a][b] = (f32x4){0.f, 0.f, 0.f, 0.f};

    // staging: 8 chunks of 16 rows; wave stages chunks {2w,2w+1}.
    // lane L: row chunk*16 + (L>>2); global seg (L&3)^((L>>3)&3) (swizzle).
    const int c0  = wave * 2;
    const int rA  = lane >> 2;
    const int gseg = ((lane & 3) ^ ((lane >> 3) & 3)) * 8;   // bf16 elems

    const bf16* gA0 = Xbf + (size_t)(i0 + c0 * 16 + rA) * KX + gseg;
    const bf16* gA1 = Xbf + (size_t)(i0 + c0 * 16 + 16 + rA) * KX + gseg;
    const bf16* gB0 = Xbf + (size_t)(j0 + c0 * 16 + rA) * KX + gseg;
    const bf16* gB1 = Xbf + (size_t)(j0 + c0 * 16 + 16 + rA) * KX + gseg;

    if (tid < 128) {
        sqxs[tid] = sqx[i0 + tid]; sqxs[128 + tid] = sqx[j0 + tid];
        sqes[tid] = sqe[i0 + tid]; sqes[128 + tid] = sqe[j0 + tid];
    }

    // fragment LDS positions (swizzled): pos = quad ^ ((l15>>1)&3)
    const int posq = (quad ^ ((l15 >> 1) & 3)) * 8;   // bf16 elems

    for (int it = 0; it < 25; ++it) {
        __syncthreads();
        gl2lds16(gA0, As + c0 * 512);
        gl2lds16(gA1, As + c0 * 512 + 512);
        gl2lds16(gB0, Bs + c0 * 512);
        gl2lds16(gB1, Bs + c0 * 512 + 512);
        gA0 += 32; gA1 += 32; gB0 += 32; gB1 += 32;
        __syncthreads();
        bf16x8 af[4], bfr[4];
        #pragma unroll
        for (int mi = 0; mi < 4; ++mi)
            af[mi] = *(const bf16x8*)&As[(wy * 64 + mi * 16 + l15) * 32 + posq];
        #pragma unroll
        for (int ni = 0; ni < 4; ++ni)
            bfr[ni] = *(const bf16x8*)&Bs[(wx * 64 + ni * 16 + l15) * 32 + posq];
        #pragma unroll
        for (int mi = 0; mi < 4; ++mi)
            #pragma unroll
            for (int ni = 0; ni < 4; ++ni)
                acc[mi][ni] = __builtin_amdgcn_mfma_f32_16x16x32_bf16(
                    af[mi], bfr[ni], acc[mi][ni], 0, 0, 0);
    }

    // one extra K-iter for the low-dim (e_to) gram; rows are 64B = same geometry
    __syncthreads();
    gl2lds16(Ebf + (size_t)(i0 + c0 * 16 + rA) * 32 + gseg,      As + c0 * 512);
    gl2lds16(Ebf + (size_t)(i0 + c0 * 16 + 16 + rA) * 32 + gseg, As + c0 * 512 + 512);
    gl2lds16(Ebf + (size_t)(j0 + c0 * 16 + rA) * 32 + gseg,      Bs + c0 * 512);
    gl2lds16(Ebf + (size_t)(j0 + c0 * 16 + 16 + rA) * 32 + gseg, Bs + c0 * 512 + 512);
    __syncthreads();
    f32x4 accE[4][4];
    {
        bf16x8 af[4], bfr[4];
        #pragma unroll
        for (int mi = 0; mi < 4; ++mi)
            af[mi] = *(const bf16x8*)&As[(wy * 64 + mi * 16 + l15) * 32 + posq];
        #pragma unroll
        for (int ni = 0; ni < 4; ++ni)
            bfr[ni] = *(const bf16x8*)&Bs[(wx * 64 + ni * 16 + l15) * 32 + posq];
        #pragma unroll
        for (int mi = 0; mi < 4; ++mi)
            #pragma unroll
            for (int ni = 0; ni < 4; ++ni) {
                f32x4 z = (f32x4){0.f, 0.f, 0.f, 0.f};
                accE[mi][ni] = __builtin_amdgcn_mfma_f32_16x16x32_bf16(
                    af[mi], bfr[ni], z, 0, 0, 0);
            }
    }

    // Epilogue. C/D layout: col = lane&15, row = quad*4 + reg  [m89/m91]
    // Row-stats (sum over j): slot 2bj+wx. Col-stats (sum over i, bi<bj only):
    // slot 2bi+wy. Per target row, slots {2bj+wx: bj>=bi} u {2bi'+wy: bi'<bi}
    // = 0..63 exactly once -> no init, no atomics.
    const int slot_r = bj * 2 + wx;
    const int slot_c = bi * 2 + wy;
    float cH[4] = {0,0,0,0}, cH2[4] = {0,0,0,0}, cL[4] = {0,0,0,0},
          cL2[4] = {0,0,0,0}, cHL[4] = {0,0,0,0};
    #pragma unroll
    for (int mi = 0; mi < 4; ++mi) {
        const int ilocb = wy * 64 + mi * 16 + quad * 4;
        float sH[4] = {0,0,0,0}, sH2[4] = {0,0,0,0}, sL[4] = {0,0,0,0},
              sL2[4] = {0,0,0,0}, sHL[4] = {0,0,0,0};
        #pragma unroll
        for (int ni = 0; ni < 4; ++ni) {
            const int jloc = wx * 64 + ni * 16 + l15;
            const int j = j0 + jloc;
            const float sqxj = sqxs[128 + jloc];
            const float sqej = sqes[128 + jloc];
            #pragma unroll
            for (int r = 0; r < 4; ++r) {
                const int iloc = ilocb + r;
                const int i = i0 + iloc;
                float H, L;
                if (i == j) { H = 0.f; L = 0.f; }
                else {
                    float d2  = sqxs[iloc] + sqxj - 2.0f * acc[mi][ni][r];
                    H = sqrtf(fmaxf(d2, 0.f));
                    float d2e = sqes[iloc] + sqej - 2.0f * accE[mi][ni][r];
                    L = sqrtf(fmaxf(d2e, 0.f));
                }
                sH[r] += H; sH2[r] += H * H; sL[r] += L; sL2[r] += L * L; sHL[r] += H * L;
                cH[ni] += H; cH2[ni] += H * H; cL[ni] += L; cL2[ni] += L * L; cHL[ni] += H * L;
            }
        }
        #pragma unroll
        for (int r = 0; r < 4; ++r) {
            float v0 = sH[r], v1 = sH2[r], v2 = sL[r], v3 = sL2[r], v4 = sHL[r];
            #pragma unroll
            for (int off = 1; off < 16; off <<= 1) {   // reduce over l15 (within quad)
                v0 += __shfl_xor(v0, off, 64);
                v1 += __shfl_xor(v1, off, 64);
                v2 += __shfl_xor(v2, off, 64);
                v3 += __shfl_xor(v3, off, 64);
                v4 += __shfl_xor(v4, off, 64);
            }
            if (l15 == 0) {
                const int i = i0 + ilocb + r;
                float* base = statsp + (size_t)slot_r * NB + i;   // [c][slot][i]
                base[0 * SLAB] = v0;
                base[1 * SLAB] = v1;
                base[2 * SLAB] = v2;
                base[3 * SLAB] = v3;
                base[4 * SLAB] = v4;
            }
        }
    }
    if (bi != bj) {
        #pragma unroll
        for (int ni = 0; ni < 4; ++ni) {
            float v0 = cH[ni], v1 = cH2[ni], v2 = cL[ni], v3 = cL2[ni], v4 = cHL[ni];
            #pragma unroll
            for (int off = 16; off < 64; off <<= 1) {   // reduce over quad
                v0 += __shfl_xor(v0, off, 64);
                v1 += __shfl_xor(v1, off, 64);
                v2 += __shfl_xor(v2, off, 64);
                v3 += __shfl_xor(v3, off, 64);
                v4 += __shfl_xor(v4, off, 64);
            }
            if (quad == 0) {
                const int j = j0 + wx * 64 + ni * 16 + l15;
                float* base = statsp + (size_t)slot_c * NB + j;
                base[0 * SLAB] = v0;
                base[1 * SLAB] = v1;
                base[2 * SLAB] = v2;
                base[3 * SLAB] = v3;
                base[4 * SLAB] = v4;
            }
        }
    }
}

// ---- finish1: reduce 64 slots per row (64 blocks, slot-quarter split), per-row corr
__global__ void finish1_kernel(const float* __restrict__ statsp, float* __restrict__ cpart) {
    __shared__ float ps2[4][64][5];
    const int t = threadIdx.x;
    const int rloc = t & 63;
    const int sg = t >> 6;
    const int r = blockIdx.x * 64 + rloc;
    float sh = 0.f, sh2 = 0.f, sl = 0.f, sl2 = 0.f, shl = 0.f;
    for (int s = sg * 16; s < sg * 16 + 16; ++s) {
        const float* base = statsp + (size_t)s * NB + r;
        sh  += base[0 * SLAB];
        sh2 += base[1 * SLAB];
        sl  += base[2 * SLAB];
        sl2 += base[3 * SLAB];
        shl += base[4 * SLAB];
    }
    ps2[sg][rloc][0] = sh; ps2[sg][rloc][1] = sh2; ps2[sg][rloc][2] = sl;
    ps2[sg][rloc][3] = sl2; ps2[sg][rloc][4] = shl;
    __syncthreads();
    if (t < 64) {
        float a = 0.f, b = 0.f, c = 0.f, d = 0.f, e = 0.f;
        #pragma unroll
        for (int g = 0; g < 4; ++g) {
            a += ps2[g][t][0]; b += ps2[g][t][1]; c += ps2[g][t][2];
            d += ps2[g][t][3]; e += ps2[g][t][4];
        }
        const float invN = 1.0f / (float)NB;
        float num = e - a * c * invN;
        float vh  = fmaxf(b - a * a * invN, 0.f);
        float vl  = fmaxf(d - c * c * invN, 0.f);
        float local = num / (sqrtf(vh) * sqrtf(vl));
        #pragma unroll
        for (int off = 32; off; off >>= 1) local += __shfl_down(local, off, 64);
        if (t == 0) cpart[blockIdx.x] = local;
    }
}

// ---- final: combine corr partials (64) + umap partials (96) -> loss
__global__ void final_kernel(const float* __restrict__ cpart, const float* __restrict__ upart,
                             float* __restrict__ out) {
    const int t = threadIdx.x;   // 128 threads
    float c = (t < 64) ? cpart[t] : 0.f;
    float u = (t < 96) ? upart[t] : 0.f;
    #pragma unroll
    for (int off = 32; off; off >>= 1) {
        c += __shfl_down(c, off, 64);
        u += __shfl_down(u, off, 64);
    }
    __shared__ float pc[2], pu[2];
    if ((t & 63) == 0) { pc[t >> 6] = c; pu[t >> 6] = u; }
    __syncthreads();
    if (t == 0) {
        float corr = (pc[0] + pc[1]) / (float)NB;
        float loss_g = -corr;
        float loss_u = (pu[0] + pu[1]) / (float)NTOT;
        out[0] = ALPHA_C * loss_u + BETA_C * loss_g;
    }
}

extern "C" void kernel_launch(void* const* d_in, const int* in_sizes, int n_in,
                              void* d_out, int out_size, void* d_ws, size_t ws_size,
                              hipStream_t stream) {
    const float* emb  = (const float*)d_in[0];   // (4096, 32) f32
    const float* ph   = (const float*)d_in[1];   // (4096, 784) f32
    const int*   perm = (const int*)d_in[2];     // (20480,) i32
    float* out = (float*)d_out;

    char* ws = (char*)d_ws;
    bf16*  Xbf    = (bf16*) (ws + WS_XBF);
    bf16*  Ebf    = (bf16*) (ws + WS_EBF);
    float* sqx    = (float*)(ws + WS_SQX);
    float* sqe    = (float*)(ws + WS_SQE);
    float* statsp = (float*)(ws + WS_STATSP);
    float* upart  = (float*)(ws + WS_UPART);
    float* cpart  = (float*)(ws + WS_CPART);

    prep_x<<<NB / 4, 256, 0, stream>>>(ph, Xbf, sqx);
    umap_prep_e<<<NTOT / 256, 256, 0, stream>>>(emb, perm, Ebf, sqe, upart);
    gram_kernel<<<NBLK, 256, 0, stream>>>(Xbf, Ebf, sqx, sqe, statsp);
    finish1_kernel<<<64, 256, 0, stream>>>(statsp, cpart);
    final_kernel<<<1, 128, 0, stream>>>(cpart, upart, out);
}

// Round 4
// 123.243 us; speedup vs baseline: 1.4381x; 1.4381x over previous
//
#include <hip/hip_runtime.h>
#include <hip/hip_bf16.h>
#include <math.h>

// Problem constants
#define NB    4096
#define DH    784
#define KX    800            // 784 padded to 25*32 for BK=32 MFMA loop
#define NSR   5
#define NNEG  (NB*NSR)       // 20480
#define NTOT  (NB + NNEG)    // 24576

#define A_CONST 1.576943f
#define PEXP    1.7901216f   // 2*B_PARAM
#define EPS_C   1.0e-4f
#define ALPHA_C 0.9296875f   // BATCH_COUNT=500: beta=0.5*(1-500/800)^2=0.0703125
#define BETA_C  0.0703125f

#define NSLOT 64             // per row: 32 block-contribs x 2 wave-halves
#define SLAB  (NB * NSLOT)   // elements per stat component = 262144
#define NBLK  528            // upper-triangular 32x32 block grid (8*66)
#define BUFE  4096           // LDS buffer stride in bf16 elems (128*32)

typedef __hip_bfloat16 bf16;
typedef short bf16x8 __attribute__((ext_vector_type(8)));
typedef float f32x4  __attribute__((ext_vector_type(4)));

// Workspace layout (bytes)
#define WS_XBF    0                      // 4096*800*2 = 6553600
#define WS_EBF    6553600                // 4096*32*2  = 262144
#define WS_SQX    6815744                // 4096*4     = 16384
#define WS_SQE    6832128                // 4096*4     = 16384
#define WS_STATSP 6848512                // 5*262144*4 = 5242880
#define WS_UPART  12091392               // 96*4       = 384
#define WS_CPART  12091776               // 64*4       = 256

__device__ __forceinline__ void gl2lds16(const bf16* g, bf16* l) {
    __builtin_amdgcn_global_load_lds(
        (const __attribute__((address_space(1))) unsigned int*)g,
        (__attribute__((address_space(3))) unsigned int*)l,
        16, 0, 0);
}

// ---- fused prep: blocks 0..1023 -> X cast+pad+sqnorm; 1024..1119 -> UMAP CE + e_to prep
__global__ void prep_fused(const float* __restrict__ X, const float* __restrict__ emb,
                           const int* __restrict__ perm, bf16* __restrict__ Xbf,
                           float* __restrict__ sqx, bf16* __restrict__ Ebf,
                           float* __restrict__ sqe, float* __restrict__ upart) {
    if (blockIdx.x < 1024) {
        // prep X: 4 waves/block, one row per wave, float4 loads. 196 float4/row.
        const int wave = threadIdx.x >> 6, lane = threadIdx.x & 63;
        const int row = blockIdx.x * 4 + wave;
        const float4* xr = (const float4*)(X + (size_t)row * DH);
        bf16* xb = Xbf + (size_t)row * KX;
        float s = 0.f;
        #pragma unroll
        for (int it = 0; it < 4; ++it) {
            const int idx = lane + it * 64;
            if (idx < 196) {
                float4 v = xr[idx];
                s += v.x * v.x + v.y * v.y + v.z * v.z + v.w * v.w;
                union { bf16 h[4]; ushort4 u; } cv;
                cv.h[0] = __float2bfloat16(v.x);
                cv.h[1] = __float2bfloat16(v.y);
                cv.h[2] = __float2bfloat16(v.z);
                cv.h[3] = __float2bfloat16(v.w);
                *(ushort4*)(xb + idx * 4) = cv.u;
            }
        }
        if (lane < 16) xb[DH + lane] = __float2bfloat16(0.f);   // pad 784..799
        #pragma unroll
        for (int off = 32; off; off >>= 1) s += __shfl_down(s, off, 64);
        if (lane == 0) sqx[row] = s;
        return;
    }
    // UMAP CE + e_to bf16 prep
    const int ub = blockIdx.x - 1024;
    const int t = ub * 256 + threadIdx.x;
    float val = 0.f;
    if (t < NB) {
        const float4* av = (const float4*)(emb + (size_t)t * 32);
        float4 t0 = av[0], t1 = av[1], t2 = av[2], t3 = av[3];   // e_to
        float4 f0 = av[4], f1 = av[5], f2 = av[6], f3 = av[7];   // e_from
        bf16* eb = Ebf + (size_t)t * 32;
        union { bf16 h[4]; ushort4 u; } cv;
        #define ST4(dst, q) cv.h[0]=__float2bfloat16(q.x); cv.h[1]=__float2bfloat16(q.y); \
                            cv.h[2]=__float2bfloat16(q.z); cv.h[3]=__float2bfloat16(q.w); \
                            *(ushort4*)(dst) = cv.u;
        ST4(eb,      t0) ST4(eb + 4,  t1) ST4(eb + 8,  t2) ST4(eb + 12, t3)
        #undef ST4
        ushort4 z = {0, 0, 0, 0};
        *(ushort4*)(eb + 16) = z; *(ushort4*)(eb + 20) = z;
        *(ushort4*)(eb + 24) = z; *(ushort4*)(eb + 28) = z;
        sqe[t] = t0.x*t0.x + t0.y*t0.y + t0.z*t0.z + t0.w*t0.w
               + t1.x*t1.x + t1.y*t1.y + t1.z*t1.z + t1.w*t1.w
               + t2.x*t2.x + t2.y*t2.y + t2.z*t2.z + t2.w*t2.w
               + t3.x*t3.x + t3.y*t3.y + t3.z*t3.z + t3.w*t3.w;
        float d2 = 0.f;
        #define D2(a, b) { float4 df = {a.x-b.x, a.y-b.y, a.z-b.z, a.w-b.w}; \
                           d2 += df.x*df.x + df.y*df.y + df.z*df.z + df.w*df.w; }
        D2(t0, f0) D2(t1, f1) D2(t2, f2) D2(t3, f3)
        #undef D2
        float d = sqrtf(d2);
        float p = 1.f / (1.f + A_CONST * powf(d, PEXP));
        val = -logf(fminf(fmaxf(p, EPS_C), 1.f));
    } else if (t < NTOT) {
        const int k = t - NB;
        const int ti = k / 5;
        const int fi = perm[k] / 5;
        const float4* at = (const float4*)(emb + (size_t)ti * 32);
        const float4* bt = (const float4*)(emb + (size_t)fi * 32 + 16);
        float d2 = 0.f;
        #pragma unroll
        for (int q = 0; q < 4; ++q) {
            float4 a = at[q], b = bt[q];
            float4 df = {a.x-b.x, a.y-b.y, a.z-b.z, a.w-b.w};
            d2 += df.x*df.x + df.y*df.y + df.z*df.z + df.w*df.w;
        }
        float d = sqrtf(d2);
        float p = 1.f / (1.f + A_CONST * powf(d, PEXP));
        val = -logf(fminf(fmaxf(1.f - p, EPS_C), 1.f));
    }
    #pragma unroll
    for (int off = 32; off; off >>= 1) val += __shfl_down(val, off, 64);
    __shared__ float ps[4];
    if ((threadIdx.x & 63) == 0) ps[threadIdx.x >> 6] = val;
    __syncthreads();
    if (threadIdx.x == 0) upart[ub] = ps[0] + ps[1] + ps[2] + ps[3];
}

// ---- main: upper-triangular 128x128 dual-gram, double-buffered K-loop,
// XOR-swizzled LDS (conflict-free), streamed E-gram epilogue, symmetric stats.
__global__ __launch_bounds__(256, 3) void gram_kernel(
    const bf16* __restrict__ Xbf, const bf16* __restrict__ Ebf,
    const float* __restrict__ sqx, const float* __restrict__ sqe,
    float* __restrict__ statsp) {
    __shared__ bf16 As[2 * BUFE];   // 16 KB (double-buffered)
    __shared__ bf16 Bs[2 * BUFE];   // 16 KB
    __shared__ float sqxs[256];     // [0..127]=i rows, [128..255]=j cols
    __shared__ float sqes[256];

    // XCD swizzle: 528 = 8*66; XCD k gets 66 consecutive triangle entries
    // (same-bi runs -> A-strip stays in that XCD's L2).
    int n = (blockIdx.x & 7) * 66 + (blockIdx.x >> 3);
    int bi = 0;
    while (n >= 32 - bi) { n -= 32 - bi; ++bi; }
    const int bj = bi + n;
    const int i0 = bi * 128, j0 = bj * 128;

    const int tid  = threadIdx.x;
    const int wave = tid >> 6;
    const int lane = tid & 63;
    const int wy = wave >> 1, wx = wave & 1;
    const int quad = lane >> 4, l15 = lane & 15;

    f32x4 acc[4][4];
    #pragma unroll
    for (int a = 0; a < 4; ++a)
        #pragma unroll
        for (int b = 0; b < 4; ++b)
            acc[a][b] = (f32x4){0.f, 0.f, 0.f, 0.f};

    // staging: 8 chunks of 16 rows; wave stages chunks {2w,2w+1}.
    // lane L: row chunk*16 + (L>>2); global seg (L&3)^((L>>3)&3) (swizzle).
    const int c0  = wave * 2;
    const int rA  = lane >> 2;
    const int gseg = ((lane & 3) ^ ((lane >> 3) & 3)) * 8;   // bf16 elems

    const bf16* gA0 = Xbf + (size_t)(i0 + c0 * 16 + rA) * KX + gseg;
    const bf16* gA1 = Xbf + (size_t)(i0 + c0 * 16 + 16 + rA) * KX + gseg;
    const bf16* gB0 = Xbf + (size_t)(j0 + c0 * 16 + rA) * KX + gseg;
    const bf16* gB1 = Xbf + (size_t)(j0 + c0 * 16 + 16 + rA) * KX + gseg;

    // prefetch iteration 0 into buffer 0
    gl2lds16(gA0, As + c0 * 512);
    gl2lds16(gA1, As + c0 * 512 + 512);
    gl2lds16(gB0, Bs + c0 * 512);
    gl2lds16(gB1, Bs + c0 * 512 + 512);
    gA0 += 32; gA1 += 32; gB0 += 32; gB1 += 32;

    if (tid < 128) {
        sqxs[tid] = sqx[i0 + tid]; sqxs[128 + tid] = sqx[j0 + tid];
        sqes[tid] = sqe[i0 + tid]; sqes[128 + tid] = sqe[j0 + tid];
    }

    // fragment LDS positions (swizzled): pos = quad ^ ((l15>>1)&3)
    const int posq = (quad ^ ((l15 >> 1) & 3)) * 8;   // bf16 elems

    for (int it = 0; it < 25; ++it) {
        __syncthreads();                      // drains prefetch of buf[it&1]
        const int cur = (it & 1) * BUFE;
        const int nxt = ((it + 1) & 1) * BUFE;
        if (it < 24) {                        // prefetch next X K-slice
            gl2lds16(gA0, As + nxt + c0 * 512);
            gl2lds16(gA1, As + nxt + c0 * 512 + 512);
            gl2lds16(gB0, Bs + nxt + c0 * 512);
            gl2lds16(gB1, Bs + nxt + c0 * 512 + 512);
            gA0 += 32; gA1 += 32; gB0 += 32; gB1 += 32;
        } else {                              // it==24: prefetch E into buf 1
            gl2lds16(Ebf + (size_t)(i0 + c0 * 16 + rA) * 32 + gseg,      As + nxt + c0 * 512);
            gl2lds16(Ebf + (size_t)(i0 + c0 * 16 + 16 + rA) * 32 + gseg, As + nxt + c0 * 512 + 512);
            gl2lds16(Ebf + (size_t)(j0 + c0 * 16 + rA) * 32 + gseg,      Bs + nxt + c0 * 512);
            gl2lds16(Ebf + (size_t)(j0 + c0 * 16 + 16 + rA) * 32 + gseg, Bs + nxt + c0 * 512 + 512);
        }
        bf16x8 af[4], bfr[4];
        #pragma unroll
        for (int mi = 0; mi < 4; ++mi)
            af[mi] = *(const bf16x8*)&As[cur + (wy * 64 + mi * 16 + l15) * 32 + posq];
        #pragma unroll
        for (int ni = 0; ni < 4; ++ni)
            bfr[ni] = *(const bf16x8*)&Bs[cur + (wx * 64 + ni * 16 + l15) * 32 + posq];
        #pragma unroll
        for (int mi = 0; mi < 4; ++mi)
            #pragma unroll
            for (int ni = 0; ni < 4; ++ni)
                acc[mi][ni] = __builtin_amdgcn_mfma_f32_16x16x32_bf16(
                    af[mi], bfr[ni], acc[mi][ni], 0, 0, 0);
    }
    __syncthreads();   // drains E prefetch (buf 1)

    // Epilogue. C/D layout: col = lane&15, row = quad*4 + reg  [m89/m91]
    // E-gram streamed per mi (4 MFMAs each) to cut register pressure.
    // Row-stats (sum over j): slot 2bj+wx. Col-stats (bi<bj): slot 2bi+wy.
    // Per target row, slots {2bj+wx: bj>=bi} u {2bi'+wy: bi'<bi} = 0..63 once.
    const int slot_r = bj * 2 + wx;
    const int slot_c = bi * 2 + wy;
    bf16x8 bfrE[4];
    #pragma unroll
    for (int ni = 0; ni < 4; ++ni)
        bfrE[ni] = *(const bf16x8*)&Bs[BUFE + (wx * 64 + ni * 16 + l15) * 32 + posq];
    float cH[4] = {0,0,0,0}, cH2[4] = {0,0,0,0}, cL[4] = {0,0,0,0},
          cL2[4] = {0,0,0,0}, cHL[4] = {0,0,0,0};
    #pragma unroll
    for (int mi = 0; mi < 4; ++mi) {
        bf16x8 afE = *(const bf16x8*)&As[BUFE + (wy * 64 + mi * 16 + l15) * 32 + posq];
        f32x4 aE[4];
        #pragma unroll
        for (int ni = 0; ni < 4; ++ni) {
            f32x4 z = (f32x4){0.f, 0.f, 0.f, 0.f};
            aE[ni] = __builtin_amdgcn_mfma_f32_16x16x32_bf16(afE, bfrE[ni], z, 0, 0, 0);
        }
        const int ilocb = wy * 64 + mi * 16 + quad * 4;
        float sH[4] = {0,0,0,0}, sH2[4] = {0,0,0,0}, sL[4] = {0,0,0,0},
              sL2[4] = {0,0,0,0}, sHL[4] = {0,0,0,0};
        #pragma unroll
        for (int ni = 0; ni < 4; ++ni) {
            const int jloc = wx * 64 + ni * 16 + l15;
            const int j = j0 + jloc;
            const float sqxj = sqxs[128 + jloc];
            const float sqej = sqes[128 + jloc];
            #pragma unroll
            for (int r = 0; r < 4; ++r) {
                const int iloc = ilocb + r;
                const int i = i0 + iloc;
                float H, L;
                if (i == j) { H = 0.f; L = 0.f; }
                else {
                    float d2  = sqxs[iloc] + sqxj - 2.0f * acc[mi][ni][r];
                    H = sqrtf(fmaxf(d2, 0.f));
                    float d2e = sqes[iloc] + sqej - 2.0f * aE[ni][r];
                    L = sqrtf(fmaxf(d2e, 0.f));
                }
                sH[r] += H; sH2[r] += H * H; sL[r] += L; sL2[r] += L * L; sHL[r] += H * L;
                cH[ni] += H; cH2[ni] += H * H; cL[ni] += L; cL2[ni] += L * L; cHL[ni] += H * L;
            }
        }
        #pragma unroll
        for (int r = 0; r < 4; ++r) {
            float v0 = sH[r], v1 = sH2[r], v2 = sL[r], v3 = sL2[r], v4 = sHL[r];
            #pragma unroll
            for (int off = 1; off < 16; off <<= 1) {   // reduce over l15 (within quad)
                v0 += __shfl_xor(v0, off, 64);
                v1 += __shfl_xor(v1, off, 64);
                v2 += __shfl_xor(v2, off, 64);
                v3 += __shfl_xor(v3, off, 64);
                v4 += __shfl_xor(v4, off, 64);
            }
            if (l15 == 0) {
                const int i = i0 + ilocb + r;
                float* base = statsp + (size_t)slot_r * NB + i;   // [c][slot][i]
                base[0 * SLAB] = v0;
                base[1 * SLAB] = v1;
                base[2 * SLAB] = v2;
                base[3 * SLAB] = v3;
                base[4 * SLAB] = v4;
            }
        }
    }
    if (bi != bj) {
        #pragma unroll
        for (int ni = 0; ni < 4; ++ni) {
            float v0 = cH[ni], v1 = cH2[ni], v2 = cL[ni], v3 = cL2[ni], v4 = cHL[ni];
            #pragma unroll
            for (int off = 16; off < 64; off <<= 1) {   // reduce over quad
                v0 += __shfl_xor(v0, off, 64);
                v1 += __shfl_xor(v1, off, 64);
                v2 += __shfl_xor(v2, off, 64);
                v3 += __shfl_xor(v3, off, 64);
                v4 += __shfl_xor(v4, off, 64);
            }
            if (quad == 0) {
                const int j = j0 + wx * 64 + ni * 16 + l15;
                float* base = statsp + (size_t)slot_c * NB + j;
                base[0 * SLAB] = v0;
                base[1 * SLAB] = v1;
                base[2 * SLAB] = v2;
                base[3 * SLAB] = v3;
                base[4 * SLAB] = v4;
            }
        }
    }
}

// ---- finish1: reduce 64 slots per row (64 blocks, slot-quarter split), per-row corr
__global__ void finish1_kernel(const float* __restrict__ statsp, float* __restrict__ cpart) {
    __shared__ float ps2[4][64][5];
    const int t = threadIdx.x;
    const int rloc = t & 63;
    const int sg = t >> 6;
    const int r = blockIdx.x * 64 + rloc;
    float sh = 0.f, sh2 = 0.f, sl = 0.f, sl2 = 0.f, shl = 0.f;
    for (int s = sg * 16; s < sg * 16 + 16; ++s) {
        const float* base = statsp + (size_t)s * NB + r;
        sh  += base[0 * SLAB];
        sh2 += base[1 * SLAB];
        sl  += base[2 * SLAB];
        sl2 += base[3 * SLAB];
        shl += base[4 * SLAB];
    }
    ps2[sg][rloc][0] = sh; ps2[sg][rloc][1] = sh2; ps2[sg][rloc][2] = sl;
    ps2[sg][rloc][3] = sl2; ps2[sg][rloc][4] = shl;
    __syncthreads();
    if (t < 64) {
        float a = 0.f, b = 0.f, c = 0.f, d = 0.f, e = 0.f;
        #pragma unroll
        for (int g = 0; g < 4; ++g) {
            a += ps2[g][t][0]; b += ps2[g][t][1]; c += ps2[g][t][2];
            d += ps2[g][t][3]; e += ps2[g][t][4];
        }
        const float invN = 1.0f / (float)NB;
        float num = e - a * c * invN;
        float vh  = fmaxf(b - a * a * invN, 0.f);
        float vl  = fmaxf(d - c * c * invN, 0.f);
        float local = num / (sqrtf(vh) * sqrtf(vl));
        #pragma unroll
        for (int off = 32; off; off >>= 1) local += __shfl_down(local, off, 64);
        if (t == 0) cpart[blockIdx.x] = local;
    }
}

// ---- final: combine corr partials (64) + umap partials (96) -> loss
__global__ void final_kernel(const float* __restrict__ cpart, const float* __restrict__ upart,
                             float* __restrict__ out) {
    const int t = threadIdx.x;   // 128 threads
    float c = (t < 64) ? cpart[t] : 0.f;
    float u = (t < 96) ? upart[t] : 0.f;
    #pragma unroll
    for (int off = 32; off; off >>= 1) {
        c += __shfl_down(c, off, 64);
        u += __shfl_down(u, off, 64);
    }
    __shared__ float pc[2], pu[2];
    if ((t & 63) == 0) { pc[t >> 6] = c; pu[t >> 6] = u; }
    __syncthreads();
    if (t == 0) {
        float corr = (pc[0] + pc[1]) / (float)NB;
        float loss_g = -corr;
        float loss_u = (pu[0] + pu[1]) / (float)NTOT;
        out[0] = ALPHA_C * loss_u + BETA_C * loss_g;
    }
}

extern "C" void kernel_launch(void* const* d_in, const int* in_sizes, int n_in,
                              void* d_out, int out_size, void* d_ws, size_t ws_size,
                              hipStream_t stream) {
    const float* emb  = (const float*)d_in[0];   // (4096, 32) f32
    const float* ph   = (const float*)d_in[1];   // (4096, 784) f32
    const int*   perm = (const int*)d_in[2];     // (20480,) i32
    float* out = (float*)d_out;

    char* ws = (char*)d_ws;
    bf16*  Xbf    = (bf16*) (ws + WS_XBF);
    bf16*  Ebf    = (bf16*) (ws + WS_EBF);
    float* sqx    = (float*)(ws + WS_SQX);
    float* sqe    = (float*)(ws + WS_SQE);
    float* statsp = (float*)(ws + WS_STATSP);
    float* upart  = (float*)(ws + WS_UPART);
    float* cpart  = (float*)(ws + WS_CPART);

    prep_fused<<<1120, 256, 0, stream>>>(ph, emb, perm, Xbf, sqx, Ebf, sqe, upart);
    gram_kernel<<<NBLK, 256, 0, stream>>>(Xbf, Ebf, sqx, sqe, statsp);
    finish1_kernel<<<64, 256, 0, stream>>>(statsp, cpart);
    final_kernel<<<1, 128, 0, stream>>>(cpart, upart, out);
}